// Round 16
// baseline (532.639 us; speedup 1.0000x reference)
//
#include <hip/hip_runtime.h>

// points [B=32, N=8192, 3] f32. FPS -> K=128 centers/batch (start 0);
// KNN -> P=32 nearest per center, ascending d2, ties by lower index.
// d_out is FLOAT32, flat concat: [idx B*K*P | centers B*K*3].
//
// R16 = R7 structure (best measured: 186.4us kernel / 227.5us bench;
// 128 blocks x 512 thr, 128 KiB LDS => 1 block/CU, 3 KNN blocks/batch +
// FPS blocks joining their batch's claim pool post-chain), HARDENED after
// R15's post-timing divergence (absmax 8087, first failure in 9 runs):
//   1. FPS chain barrier = plain __syncthreads() (not inline-asm
//      s_barrier). Measured-free: R2 (syncthreads, full vmcnt drain every
//      step) == R3 (asm barrier, no drain) == 195.5us. Removes the
//      hand-rolled-barrier risk surface (guide rule #18).
//   2. publish = RELEASE, poll = ACQUIRE (agent scope). Closes all
//      memory-model holes; release's drain is subsumed by the barrier
//      drain (measured free), acquire cost sits in the consumer's wait.
//   blocks 0..31 : FPS (512 thr x 16 pts, 8 waves — optimal: 16 waves
//                  +28us R4, 4 waves +6us R8). Publishes each center to
//                  d_ws the moment it is known; joins claim pool after.
//   blocks 32..127: 3 KNN blocks/batch (optimal: 224blk=195, 128blk=186,
//                  96blk=211). Waves CLAIM centers from a per-batch
//                  atomic counter, poll sentinel-validated words
//                  (0xFFFFFFFF = NaN, impossible for finite coords).
// Bit-parity: per-thread ascending-idx visit order keeps lowest idx on
// value ties; the u64 reduce sees the same 8192 (val,idx) pairs under any
// partition. Deadlock-free: one-way dependency + co-residency by LDS
// arithmetic (128 blocks x 128KiB => every block gets its own CU).
#define BB 32
#define NN 8192
#define KK 128
#define PP 32
#define IDX_COUNT (BB * KK * PP)      // 131072
#define XCHG_WORDS (BB * KK * 3)      // 12288 center words
#define CLEAR_WORDS (XCHG_WORDS + BB) // + 32 claim counters
#define KNN_PER_B 3
#define NBLK (BB + BB * KNN_PER_B)    // 128

// ---- DPP wave64 reductions (VALU-only) ------------------------------------
// row_shr:1/2/4/8 then row_bcast15/31; lane 63 holds the result.
#define DPP_RED_U64(v, CMP)                                                   \
    {                                                                         \
        _Pragma("unroll")                                                     \
        for (int s = 0; s < 6; ++s) {                                         \
            const int ctrl = (s == 0) ? 0x111 : (s == 1) ? 0x112 :            \
                             (s == 2) ? 0x114 : (s == 3) ? 0x118 :            \
                             (s == 4) ? 0x142 : 0x143;                        \
            unsigned lo = (unsigned)v, hi = (unsigned)(v >> 32);              \
            unsigned slo, shi;                                                \
            switch (ctrl) {                                                   \
            case 0x111:                                                       \
                slo = (unsigned)__builtin_amdgcn_update_dpp((int)lo, (int)lo, 0x111, 0xf, 0xf, false); \
                shi = (unsigned)__builtin_amdgcn_update_dpp((int)hi, (int)hi, 0x111, 0xf, 0xf, false); break; \
            case 0x112:                                                       \
                slo = (unsigned)__builtin_amdgcn_update_dpp((int)lo, (int)lo, 0x112, 0xf, 0xf, false); \
                shi = (unsigned)__builtin_amdgcn_update_dpp((int)hi, (int)hi, 0x112, 0xf, 0xf, false); break; \
            case 0x114:                                                       \
                slo = (unsigned)__builtin_amdgcn_update_dpp((int)lo, (int)lo, 0x114, 0xf, 0xf, false); \
                shi = (unsigned)__builtin_amdgcn_update_dpp((int)hi, (int)hi, 0x114, 0xf, 0xf, false); break; \
            case 0x118:                                                       \
                slo = (unsigned)__builtin_amdgcn_update_dpp((int)lo, (int)lo, 0x118, 0xf, 0xf, false); \
                shi = (unsigned)__builtin_amdgcn_update_dpp((int)hi, (int)hi, 0x118, 0xf, 0xf, false); break; \
            case 0x142:                                                       \
                slo = (unsigned)__builtin_amdgcn_update_dpp((int)lo, (int)lo, 0x142, 0xf, 0xf, false); \
                shi = (unsigned)__builtin_amdgcn_update_dpp((int)hi, (int)hi, 0x142, 0xf, 0xf, false); break; \
            default:                                                          \
                slo = (unsigned)__builtin_amdgcn_update_dpp((int)lo, (int)lo, 0x143, 0xf, 0xf, false); \
                shi = (unsigned)__builtin_amdgcn_update_dpp((int)hi, (int)hi, 0x143, 0xf, 0xf, false); break; \
            }                                                                 \
            const unsigned long long sv = ((unsigned long long)shi << 32) | slo; \
            if (sv CMP v) v = sv;                                             \
        }                                                                     \
    }

__device__ __forceinline__ unsigned long long readlane63_u64(unsigned long long v) {
    const unsigned lo = (unsigned)__builtin_amdgcn_readlane((int)(unsigned)v, 63);
    const unsigned hi = (unsigned)__builtin_amdgcn_readlane((int)(unsigned)(v >> 32), 63);
    return ((unsigned long long)hi << 32) | lo;
}

// RELEASE publish / ACQUIRE poll, agent scope. Words self-validate via the
// 0xFFFFFFFF sentinel (NaN bit pattern, impossible for finite coords); the
// release/acquire pair additionally rules out any ordering/visibility hole.
__device__ __forceinline__ void publish_word(unsigned* p, float v) {
    __hip_atomic_store(p, __float_as_uint(v), __ATOMIC_RELEASE,
                       __HIP_MEMORY_SCOPE_AGENT);
}
__device__ __forceinline__ float poll_word(const unsigned* p) {
    unsigned u = __hip_atomic_load(p, __ATOMIC_ACQUIRE, __HIP_MEMORY_SCOPE_AGENT);
    while (u == 0xFFFFFFFFu) {
        __builtin_amdgcn_s_sleep(8);   // ~512 cyc backoff
        u = __hip_atomic_load(p, __ATOMIC_ACQUIRE, __HIP_MEMORY_SCOPE_AGENT);
    }
    return __uint_as_float(u);
}

// Dual-array sorted insert, compare on d-bits strict-< (bit-parity: per-lane
// ascending-idx visit order == idx tie-break). 4 u32 cmps + 16 selects.
#define CACHE_INS2(dd, ii, d1, i1, d2, i2, d3, i3, d4, i4)              \
    {                                                                   \
        const bool c1 = (dd) < d1, c2 = (dd) < d2,                      \
                   c3 = (dd) < d3, c4 = (dd) < d4;                      \
        d4 = c3 ? d3 : (c4 ? (dd) : d4);  i4 = c3 ? i3 : (c4 ? (ii) : i4); \
        d3 = c2 ? d2 : (c3 ? (dd) : d3);  i3 = c2 ? i2 : (c3 ? (ii) : i3); \
        d2 = c1 ? d1 : (c2 ? (dd) : d2);  i2 = c1 ? i1 : (c2 ? (ii) : i2); \
        d1 = c1 ? (dd) : d1;              i1 = c1 ? (ii) : i1;          \
    }

// One center's exact KNN for one wave. SRC=0: float4(x,y,z,pp) LDS cloud;
// SRC=1: packed xyz LDS cloud (FPS block's pts3), pp computed on the fly
// (same expression/order as SRC=0 staging, contract off => bit-identical,
// so results are executor-independent under the dynamic claim assignment).
template <int SRC>
__device__ __forceinline__ void knn_one_center(
    const float* __restrict__ ldsf, const int lane,
    const float cx, const float cy, const float cz,
    float* __restrict__ outp)
{
#pragma clang fp contract(off)
    const float cc = (cx * cx + cy * cy) + cz * cz;
    unsigned d1 = ~0u, i1 = ~0u, d2_ = ~0u, i2 = ~0u,
             d3 = ~0u, i3 = ~0u, d4 = ~0u, i4 = ~0u;
#pragma unroll 4
    for (int i = 0; i < 128; ++i) {
        const int idx = lane + i * 64;
        float qx, qy, qz, qw;
        if constexpr (SRC == 0) {
            const float4 q = ((const float4*)ldsf)[idx];
            qx = q.x; qy = q.y; qz = q.z; qw = q.w;
        } else {
            qx = ldsf[idx * 3 + 0]; qy = ldsf[idx * 3 + 1]; qz = ldsf[idx * 3 + 2];
            qw = (qx * qx + qy * qy) + qz * qz;
        }
        const float dot = (cx * qx + cy * qy) + cz * qz;
        float dd2 = (cc + qw) - (2.0f * dot);
        dd2 = dd2 + 0.0f;                                   // -0.0 -> +0.0
        unsigned u = __float_as_uint(dd2);
        u = (u & 0x80000000u) ? ~u : (u | 0x80000000u);     // ordered-uint
        CACHE_INS2(u, (unsigned)idx, d1, i1, d2_, i2, d3, i3, d4, i4);
    }

    float resv = 0.0f;
    for (int j = 0; j < PP; ++j) {
        unsigned long long r = ((unsigned long long)d1 << 32) | i1;
        DPP_RED_U64(r, <);                        // lane 63 authoritative
        const unsigned long long best = readlane63_u64(r);
        if (lane == j) resv = (float)(unsigned)(best & 0xFFFFFFFFu);
        if (((((unsigned long long)d1 << 32) | i1)) == best) {   // pop owner
            d1 = d2_; i1 = i2; d2_ = d3; i2 = i3; d3 = d4; i3 = i4;
            d4 = ~0u; i4 = ~0u;
        }
        if (d1 == ~0u) {                          // rare exact refill
            for (int i = 0; i < 128; ++i) {
                const int idx = lane + i * 64;
                float qx, qy, qz, qw;
                if constexpr (SRC == 0) {
                    const float4 q = ((const float4*)ldsf)[idx];
                    qx = q.x; qy = q.y; qz = q.z; qw = q.w;
                } else {
                    qx = ldsf[idx * 3 + 0]; qy = ldsf[idx * 3 + 1]; qz = ldsf[idx * 3 + 2];
                    qw = (qx * qx + qy * qy) + qz * qz;
                }
                const float dot = (cx * qx + cy * qy) + cz * qz;
                float dd2 = (cc + qw) - (2.0f * dot);
                dd2 = dd2 + 0.0f;
                unsigned u = __float_as_uint(dd2);
                u = (u & 0x80000000u) ? ~u : (u | 0x80000000u);
                const unsigned long long kk2 =
                    ((unsigned long long)u << 32) | (unsigned)idx;
                if (kk2 > best)
                    CACHE_INS2(u, (unsigned)idx, d1, i1, d2_, i2, d3, i3, d4, i4);
            }
        }
    }
    if (lane < PP) outp[lane] = resv;             // 128 B/wave
}

__global__ __launch_bounds__(1024) void clear_kernel(unsigned* __restrict__ xchg) {
    const int i = blockIdx.x * 1024 + threadIdx.x;
    if (i < XCHG_WORDS) xchg[i] = 0xFFFFFFFFu;       // center sentinels
    else if (i < CLEAR_WORDS) xchg[i] = 0u;          // claim counters
}

__global__ __launch_bounds__(512) void fused_kernel(
    const float* __restrict__ pts, float* __restrict__ out,
    unsigned* __restrict__ xchg)
{
#pragma clang fp contract(off)
    // 128 KiB raw LDS => hard 1 block/CU (residency: 128 blocks <= 256 CUs).
    __shared__ __align__(16) unsigned char smem_raw[131072];
    const int t = threadIdx.x;
    const int lane = t & 63, wid = t >> 6;
    unsigned* claims = xchg + XCHG_WORDS;

    if (blockIdx.x < BB) {
        // ---------------- FPS producer (R7 chain, plain barriers) --------
        const int b = blockIdx.x;
        const float* p = pts + (size_t)b * NN * 3;
        float* pts3 = (float*)smem_raw;                        // 96 KB
        float* cbuf = (float*)(smem_raw + 98304);              // 1.5 KB
        unsigned long long* wkf =
            (unsigned long long*)(smem_raw + 98304 + 1536);    // [2][8]

        if (t == 0) {   // publish center 0 (= point 0) immediately
            unsigned* dst = xchg + (unsigned)b * KK * 3u;
            publish_word(dst + 0, p[0]);
            publish_word(dst + 1, p[1]);
            publish_word(dst + 2, p[2]);
        }

        float px[16], py[16], pz[16], mind[16];
#pragma unroll
        for (int i = 0; i < 16; ++i) {
            const int idx = t + i * 512;
            const float x = p[idx * 3 + 0], y = p[idx * 3 + 1], z = p[idx * 3 + 2];
            px[i] = x; py[i] = y; pz[i] = z; mind[i] = __builtin_inff();
            pts3[idx * 3 + 0] = x; pts3[idx * 3 + 1] = y; pts3[idx * 3 + 2] = z;
        }
        __syncthreads();

        float lx = pts3[0], ly = pts3[1], lz = pts3[2];
        if (t == 0) { cbuf[0] = lx; cbuf[1] = ly; cbuf[2] = lz; }

        for (int k = 0; k < KK - 1; ++k) {       // 127 serial steps
            float best = -1.0f; unsigned bidx = 0;
#pragma unroll
            for (int i = 0; i < 16; ++i) {
                const float dx = px[i] - lx, dy = py[i] - ly, dz = pz[i] - lz;
                const float d = (dx * dx + dy * dy) + dz * dz;
                const float m = mind[i] < d ? mind[i] : d;
                mind[i] = m;
                if (m > best) { best = m; bidx = (unsigned)(t + i * 512); }
            }
            union { float f; unsigned u; } cv; cv.f = best;   // best >= 0
            unsigned long long key = ((unsigned long long)cv.u << 32)
                                   | (0xFFFFFFFFu - bidx);    // low-idx tie-break
            DPP_RED_U64(key, >);                  // lane 63 authoritative
            if (lane == 63) wkf[(k & 1) * 8 + wid] = key;
            __syncthreads();   // full drain (incl. publish stores): R2
                               // measured this pattern == no-drain (R3).
            unsigned long long w = wkf[(k & 1) * 8];
#pragma unroll
            for (int i = 1; i < 8; ++i) {
                const unsigned long long o = wkf[(k & 1) * 8 + i];
                if (o > w) w = o;
            }
            const unsigned last = 0xFFFFFFFFu - (unsigned)(w & 0xFFFFFFFFu);
            lx = pts3[last * 3 + 0];              // broadcast reads
            ly = pts3[last * 3 + 1];
            lz = pts3[last * 3 + 2];
            if (t == 0) {
                cbuf[(k + 1) * 3 + 0] = lx;
                cbuf[(k + 1) * 3 + 1] = ly;
                cbuf[(k + 1) * 3 + 2] = lz;
                unsigned* dst = xchg + ((unsigned)b * KK + (unsigned)(k + 1)) * 3u;
                publish_word(dst + 0, lx);        // release stores
                publish_word(dst + 1, ly);
                publish_word(dst + 2, lz);
            }
        }
        __syncthreads();
        if (t < KK * 3)
            out[IDX_COUNT + b * (KK * 3) + t] = cbuf[t];

        // ------- chain done: JOIN the claim pool for this batch ----------
        // Coords from cbuf (LDS), points from pts3 (LDS) — no polling, no
        // restaging. Adds 32 CUs exactly when the tail risk peaks.
        for (;;) {
            unsigned m = 0;
            if (lane == 0) m = atomicAdd(claims + b, 1u);
            m = (unsigned)__builtin_amdgcn_readfirstlane((int)m);
            if (m >= KK) break;
            const int c = (int)m;
            const float cx = cbuf[c * 3 + 0];
            const float cy = cbuf[c * 3 + 1];
            const float cz = cbuf[c * 3 + 2];
            knn_one_center<1>(pts3, lane, cx, cy, cz,
                              out + (size_t)(b * KK + c) * PP);
        }
    } else {
        // ------------------------- KNN consumer --------------------------
        const int blk = blockIdx.x - BB;          // 0..95
        const int b = blk / KNN_PER_B;            // 3 blocks/batch
        float4* sp = (float4*)smem_raw;           // 128 KB
        const float* p = pts + (size_t)b * NN * 3;
#pragma unroll
        for (int i = 0; i < 16; ++i) {
            const int idx = t + i * 512;
            const float x = p[idx * 3 + 0], y = p[idx * 3 + 1], z = p[idx * 3 + 2];
            sp[idx] = make_float4(x, y, z, (x * x + y * y) + z * z);
        }
        __syncthreads();   // only barrier; afterwards waves run independently

        for (;;) {
            unsigned m = 0;
            if (lane == 0) m = atomicAdd(claims + b, 1u);
            m = (unsigned)__builtin_amdgcn_readfirstlane((int)m);
            if (m >= KK) break;
            const int c = (int)m;

            const unsigned* src = xchg + ((unsigned)b * KK + (unsigned)c) * 3u;
            const float cx = poll_word(src + 0);
            const float cy = poll_word(src + 1);
            const float cz = poll_word(src + 2);
            knn_one_center<0>((const float*)sp, lane, cx, cy, cz,
                              out + (size_t)(b * KK + c) * PP);
        }
    }
}

// ------------------------- fallback (ws too small) -------------------------
__global__ __launch_bounds__(512) void fps_kernel(
    const float* __restrict__ pts, float* __restrict__ out)
{
#pragma clang fp contract(off)
    const int b = blockIdx.x;
    const int t = threadIdx.x;
    const float* p = pts + (size_t)b * NN * 3;

    __shared__ float pts3[NN * 3];
    __shared__ float cbuf[KK * 3];
    __shared__ unsigned long long wk[2][8];

    float px[16], py[16], pz[16], mind[16];
#pragma unroll
    for (int i = 0; i < 16; ++i) {
        const int idx = t + i * 512;
        const float x = p[idx * 3 + 0], y = p[idx * 3 + 1], z = p[idx * 3 + 2];
        px[i] = x; py[i] = y; pz[i] = z; mind[i] = __builtin_inff();
        pts3[idx * 3 + 0] = x; pts3[idx * 3 + 1] = y; pts3[idx * 3 + 2] = z;
    }
    __syncthreads();

    float lx = pts3[0], ly = pts3[1], lz = pts3[2];
    if (t == 0) { cbuf[0] = lx; cbuf[1] = ly; cbuf[2] = lz; }
    const int lane = t & 63, wid = t >> 6;

    for (int k = 0; k < KK - 1; ++k) {
        float best = -1.0f; unsigned bidx = 0;
#pragma unroll
        for (int i = 0; i < 16; ++i) {
            const float dx = px[i] - lx, dy = py[i] - ly, dz = pz[i] - lz;
            const float d = (dx * dx + dy * dy) + dz * dz;
            const float m = mind[i] < d ? mind[i] : d;
            mind[i] = m;
            if (m > best) { best = m; bidx = (unsigned)(t + i * 512); }
        }
        union { float f; unsigned u; } cv; cv.f = best;
        unsigned long long key = ((unsigned long long)cv.u << 32)
                               | (0xFFFFFFFFu - bidx);
        DPP_RED_U64(key, >);
        if (lane == 63) wk[k & 1][wid] = key;
        __syncthreads();
        unsigned long long w = wk[k & 1][0];
#pragma unroll
        for (int i = 1; i < 8; ++i) {
            const unsigned long long o = wk[k & 1][i];
            if (o > w) w = o;
        }
        const unsigned last = 0xFFFFFFFFu - (unsigned)(w & 0xFFFFFFFFu);
        lx = pts3[last * 3 + 0];
        ly = pts3[last * 3 + 1];
        lz = pts3[last * 3 + 2];
        if (t == 0) {
            cbuf[(k + 1) * 3 + 0] = lx;
            cbuf[(k + 1) * 3 + 1] = ly;
            cbuf[(k + 1) * 3 + 2] = lz;
        }
    }
    __syncthreads();
    if (t < KK * 3)
        out[IDX_COUNT + b * (KK * 3) + t] = cbuf[t];
}

__global__ __launch_bounds__(1024) void knn_kernel(
    const float* __restrict__ pts, float* __restrict__ out)
{
#pragma clang fp contract(off)
    const int t = threadIdx.x, lane = t & 63, wid = t >> 6;
    const int blk = blockIdx.x;
    const int b = blk >> 3;
    const int bk = b * KK + (blk & 7) * 16 + wid;

    __shared__ float4 sp[NN];
    const float* p = pts + (size_t)b * NN * 3;
#pragma unroll
    for (int i = 0; i < 8; ++i) {
        const int idx = t + i * 1024;
        const float x = p[idx * 3 + 0], y = p[idx * 3 + 1], z = p[idx * 3 + 2];
        sp[idx] = make_float4(x, y, z, (x * x + y * y) + z * z);
    }

    const float cx = out[IDX_COUNT + bk * 3 + 0];
    const float cy = out[IDX_COUNT + bk * 3 + 1];
    const float cz = out[IDX_COUNT + bk * 3 + 2];
    __syncthreads();

    knn_one_center<0>((const float*)sp, lane, cx, cy, cz,
                      out + (size_t)bk * PP);
}

extern "C" void kernel_launch(void* const* d_in, const int* in_sizes, int n_in,
                              void* d_out, int out_size, void* d_ws, size_t ws_size,
                              hipStream_t stream) {
    const float* pts = (const float*)d_in[0];
    float* out = (float*)d_out;   // f32: [idx 131072 | centers 12288]

    if (ws_size >= (size_t)(CLEAR_WORDS * 4)) {
        clear_kernel<<<(CLEAR_WORDS + 1023) / 1024, 1024, 0, stream>>>(
            (unsigned*)d_ws);
        fused_kernel<<<NBLK, 512, 0, stream>>>(pts, out, (unsigned*)d_ws);
    } else {
        fps_kernel<<<BB, 512, 0, stream>>>(pts, out);
        knn_kernel<<<BB * 8, 1024, 0, stream>>>(pts, out);
    }
}

// Round 19
// 227.476 us; speedup vs baseline: 2.3415x; 2.3415x over previous
//
#include <hip/hip_runtime.h>

// points [B=32, N=8192, 3] f32. FPS -> K=128 centers/batch (start 0);
// KNN -> P=32 nearest per center, ascending d2, ties by lower index.
// d_out is FLOAT32, flat concat: [idx B*K*P | centers B*K*3].
//
// R17 = R7 structure (best measured: 186.4us kernel / 227.5us bench;
// 128 blocks x 512 thr, 128 KiB LDS => 1 block/CU, 3 KNN blocks/batch +
// FPS blocks joining their batch's claim pool post-chain) with the R16
// barrier hardening kept and the R16 atomic-ordering cost removed:
//   - FPS chain barrier = plain __syncthreads() (compiler-blessed; no
//     inline-asm s_barrier => removes the only code-level suspect for
//     R15's one-off divergence, per guide rule #18). Measured free:
//     R2 (syncthreads, full drain) == R3 (asm barrier, no drain).
//   - publish/poll = RELAXED agent scope. Provably sufficient: each
//     exchange word has exactly two writers ever (clear-kernel sentinel
//     0xFFFFFFFF, then ONE publish of a finite float, separated by a
//     kernel-dispatch boundary), so a relaxed load returns either the
//     sentinel or the correct value — no cross-word ordering exists to
//     protect. R16's release/acquire (L2 writeback/invalidate per op on
//     non-coherent-L2 gfx950) cost 2.7x (kernel 186 -> 500us).
//   blocks 0..31 : FPS (512 thr x 16 pts, 8 waves — optimal: 16 waves
//                  +28us R4, 4 waves +6us R8/R11). Publishes each center
//                  to d_ws the moment it is known; joins claim pool after.
//   blocks 32..127: 3 KNN blocks/batch (optimal: 224blk=195, 128blk=186,
//                  96blk=211). Waves CLAIM centers from a per-batch
//                  atomic counter, poll sentinel-validated words.
// Bit-parity: per-thread ascending-idx visit order keeps lowest idx on
// value ties; the u64 reduce sees the same 8192 (val,idx) pairs under any
// partition. Deadlock-free: one-way dependency + co-residency by LDS
// arithmetic (128 blocks x 128KiB => every block gets its own CU).
#define BB 32
#define NN 8192
#define KK 128
#define PP 32
#define IDX_COUNT (BB * KK * PP)      // 131072
#define XCHG_WORDS (BB * KK * 3)      // 12288 center words
#define CLEAR_WORDS (XCHG_WORDS + BB) // + 32 claim counters
#define KNN_PER_B 3
#define NBLK (BB + BB * KNN_PER_B)    // 128

// ---- DPP wave64 reductions (VALU-only) ------------------------------------
// row_shr:1/2/4/8 then row_bcast15/31; lane 63 holds the result.
#define DPP_RED_U64(v, CMP)                                                   \
    {                                                                         \
        _Pragma("unroll")                                                     \
        for (int s = 0; s < 6; ++s) {                                         \
            const int ctrl = (s == 0) ? 0x111 : (s == 1) ? 0x112 :            \
                             (s == 2) ? 0x114 : (s == 3) ? 0x118 :            \
                             (s == 4) ? 0x142 : 0x143;                        \
            unsigned lo = (unsigned)v, hi = (unsigned)(v >> 32);              \
            unsigned slo, shi;                                                \
            switch (ctrl) {                                                   \
            case 0x111:                                                       \
                slo = (unsigned)__builtin_amdgcn_update_dpp((int)lo, (int)lo, 0x111, 0xf, 0xf, false); \
                shi = (unsigned)__builtin_amdgcn_update_dpp((int)hi, (int)hi, 0x111, 0xf, 0xf, false); break; \
            case 0x112:                                                       \
                slo = (unsigned)__builtin_amdgcn_update_dpp((int)lo, (int)lo, 0x112, 0xf, 0xf, false); \
                shi = (unsigned)__builtin_amdgcn_update_dpp((int)hi, (int)hi, 0x112, 0xf, 0xf, false); break; \
            case 0x114:                                                       \
                slo = (unsigned)__builtin_amdgcn_update_dpp((int)lo, (int)lo, 0x114, 0xf, 0xf, false); \
                shi = (unsigned)__builtin_amdgcn_update_dpp((int)hi, (int)hi, 0x114, 0xf, 0xf, false); break; \
            case 0x118:                                                       \
                slo = (unsigned)__builtin_amdgcn_update_dpp((int)lo, (int)lo, 0x118, 0xf, 0xf, false); \
                shi = (unsigned)__builtin_amdgcn_update_dpp((int)hi, (int)hi, 0x118, 0xf, 0xf, false); break; \
            case 0x142:                                                       \
                slo = (unsigned)__builtin_amdgcn_update_dpp((int)lo, (int)lo, 0x142, 0xf, 0xf, false); \
                shi = (unsigned)__builtin_amdgcn_update_dpp((int)hi, (int)hi, 0x142, 0xf, 0xf, false); break; \
            default:                                                          \
                slo = (unsigned)__builtin_amdgcn_update_dpp((int)lo, (int)lo, 0x143, 0xf, 0xf, false); \
                shi = (unsigned)__builtin_amdgcn_update_dpp((int)hi, (int)hi, 0x143, 0xf, 0xf, false); break; \
            }                                                                 \
            const unsigned long long sv = ((unsigned long long)shi << 32) | slo; \
            if (sv CMP v) v = sv;                                             \
        }                                                                     \
    }

__device__ __forceinline__ unsigned long long readlane63_u64(unsigned long long v) {
    const unsigned lo = (unsigned)__builtin_amdgcn_readlane((int)(unsigned)v, 63);
    const unsigned hi = (unsigned)__builtin_amdgcn_readlane((int)(unsigned)(v >> 32), 63);
    return ((unsigned long long)hi << 32) | lo;
}

// RELAXED agent-scope publish/poll. Each word has exactly two writers ever
// (clear-kernel sentinel, then one publish of a finite float, separated by
// a dispatch boundary) => a relaxed load returns sentinel or the correct
// value; no cross-word ordering exists to protect. (R16's release/acquire
// on non-coherent-L2 gfx950 cost 2.7x via per-op cache maintenance.)
__device__ __forceinline__ void publish_word(unsigned* p, float v) {
    __hip_atomic_store(p, __float_as_uint(v), __ATOMIC_RELAXED,
                       __HIP_MEMORY_SCOPE_AGENT);
}
__device__ __forceinline__ float poll_word(const unsigned* p) {
    unsigned u = __hip_atomic_load(p, __ATOMIC_RELAXED, __HIP_MEMORY_SCOPE_AGENT);
    while (u == 0xFFFFFFFFu) {
        __builtin_amdgcn_s_sleep(8);   // ~512 cyc backoff
        u = __hip_atomic_load(p, __ATOMIC_RELAXED, __HIP_MEMORY_SCOPE_AGENT);
    }
    return __uint_as_float(u);
}

// Dual-array sorted insert, compare on d-bits strict-< (bit-parity: per-lane
// ascending-idx visit order == idx tie-break). 4 u32 cmps + 16 selects.
#define CACHE_INS2(dd, ii, d1, i1, d2, i2, d3, i3, d4, i4)              \
    {                                                                   \
        const bool c1 = (dd) < d1, c2 = (dd) < d2,                      \
                   c3 = (dd) < d3, c4 = (dd) < d4;                      \
        d4 = c3 ? d3 : (c4 ? (dd) : d4);  i4 = c3 ? i3 : (c4 ? (ii) : i4); \
        d3 = c2 ? d2 : (c3 ? (dd) : d3);  i3 = c2 ? i2 : (c3 ? (ii) : i3); \
        d2 = c1 ? d1 : (c2 ? (dd) : d2);  i2 = c1 ? i1 : (c2 ? (ii) : i2); \
        d1 = c1 ? (dd) : d1;              i1 = c1 ? (ii) : i1;          \
    }

// One center's exact KNN for one wave. SRC=0: float4(x,y,z,pp) LDS cloud;
// SRC=1: packed xyz LDS cloud (FPS block's pts3), pp computed on the fly
// (same expression/order as SRC=0 staging, contract off => bit-identical,
// so results are executor-independent under the dynamic claim assignment).
template <int SRC>
__device__ __forceinline__ void knn_one_center(
    const float* __restrict__ ldsf, const int lane,
    const float cx, const float cy, const float cz,
    float* __restrict__ outp)
{
#pragma clang fp contract(off)
    const float cc = (cx * cx + cy * cy) + cz * cz;
    unsigned d1 = ~0u, i1 = ~0u, d2_ = ~0u, i2 = ~0u,
             d3 = ~0u, i3 = ~0u, d4 = ~0u, i4 = ~0u;
#pragma unroll 4
    for (int i = 0; i < 128; ++i) {
        const int idx = lane + i * 64;
        float qx, qy, qz, qw;
        if constexpr (SRC == 0) {
            const float4 q = ((const float4*)ldsf)[idx];
            qx = q.x; qy = q.y; qz = q.z; qw = q.w;
        } else {
            qx = ldsf[idx * 3 + 0]; qy = ldsf[idx * 3 + 1]; qz = ldsf[idx * 3 + 2];
            qw = (qx * qx + qy * qy) + qz * qz;
        }
        const float dot = (cx * qx + cy * qy) + cz * qz;
        float dd2 = (cc + qw) - (2.0f * dot);
        dd2 = dd2 + 0.0f;                                   // -0.0 -> +0.0
        unsigned u = __float_as_uint(dd2);
        u = (u & 0x80000000u) ? ~u : (u | 0x80000000u);     // ordered-uint
        CACHE_INS2(u, (unsigned)idx, d1, i1, d2_, i2, d3, i3, d4, i4);
    }

    float resv = 0.0f;
    for (int j = 0; j < PP; ++j) {
        unsigned long long r = ((unsigned long long)d1 << 32) | i1;
        DPP_RED_U64(r, <);                        // lane 63 authoritative
        const unsigned long long best = readlane63_u64(r);
        if (lane == j) resv = (float)(unsigned)(best & 0xFFFFFFFFu);
        if (((((unsigned long long)d1 << 32) | i1)) == best) {   // pop owner
            d1 = d2_; i1 = i2; d2_ = d3; i2 = i3; d3 = d4; i3 = i4;
            d4 = ~0u; i4 = ~0u;
        }
        if (d1 == ~0u) {                          // rare exact refill
            for (int i = 0; i < 128; ++i) {
                const int idx = lane + i * 64;
                float qx, qy, qz, qw;
                if constexpr (SRC == 0) {
                    const float4 q = ((const float4*)ldsf)[idx];
                    qx = q.x; qy = q.y; qz = q.z; qw = q.w;
                } else {
                    qx = ldsf[idx * 3 + 0]; qy = ldsf[idx * 3 + 1]; qz = ldsf[idx * 3 + 2];
                    qw = (qx * qx + qy * qy) + qz * qz;
                }
                const float dot = (cx * qx + cy * qy) + cz * qz;
                float dd2 = (cc + qw) - (2.0f * dot);
                dd2 = dd2 + 0.0f;
                unsigned u = __float_as_uint(dd2);
                u = (u & 0x80000000u) ? ~u : (u | 0x80000000u);
                const unsigned long long kk2 =
                    ((unsigned long long)u << 32) | (unsigned)idx;
                if (kk2 > best)
                    CACHE_INS2(u, (unsigned)idx, d1, i1, d2_, i2, d3, i3, d4, i4);
            }
        }
    }
    if (lane < PP) outp[lane] = resv;             // 128 B/wave
}

__global__ __launch_bounds__(1024) void clear_kernel(unsigned* __restrict__ xchg) {
    const int i = blockIdx.x * 1024 + threadIdx.x;
    if (i < XCHG_WORDS) xchg[i] = 0xFFFFFFFFu;       // center sentinels
    else if (i < CLEAR_WORDS) xchg[i] = 0u;          // claim counters
}

__global__ __launch_bounds__(512) void fused_kernel(
    const float* __restrict__ pts, float* __restrict__ out,
    unsigned* __restrict__ xchg)
{
#pragma clang fp contract(off)
    // 128 KiB raw LDS => hard 1 block/CU (residency: 128 blocks <= 256 CUs).
    __shared__ __align__(16) unsigned char smem_raw[131072];
    const int t = threadIdx.x;
    const int lane = t & 63, wid = t >> 6;
    unsigned* claims = xchg + XCHG_WORDS;

    if (blockIdx.x < BB) {
        // ---------------- FPS producer (R7 chain, plain barriers) --------
        const int b = blockIdx.x;
        const float* p = pts + (size_t)b * NN * 3;
        float* pts3 = (float*)smem_raw;                        // 96 KB
        float* cbuf = (float*)(smem_raw + 98304);              // 1.5 KB
        unsigned long long* wkf =
            (unsigned long long*)(smem_raw + 98304 + 1536);    // [2][8]

        if (t == 0) {   // publish center 0 (= point 0) immediately
            unsigned* dst = xchg + (unsigned)b * KK * 3u;
            publish_word(dst + 0, p[0]);
            publish_word(dst + 1, p[1]);
            publish_word(dst + 2, p[2]);
        }

        float px[16], py[16], pz[16], mind[16];
#pragma unroll
        for (int i = 0; i < 16; ++i) {
            const int idx = t + i * 512;
            const float x = p[idx * 3 + 0], y = p[idx * 3 + 1], z = p[idx * 3 + 2];
            px[i] = x; py[i] = y; pz[i] = z; mind[i] = __builtin_inff();
            pts3[idx * 3 + 0] = x; pts3[idx * 3 + 1] = y; pts3[idx * 3 + 2] = z;
        }
        __syncthreads();

        float lx = pts3[0], ly = pts3[1], lz = pts3[2];
        if (t == 0) { cbuf[0] = lx; cbuf[1] = ly; cbuf[2] = lz; }

        for (int k = 0; k < KK - 1; ++k) {       // 127 serial steps
            float best = -1.0f; unsigned bidx = 0;
#pragma unroll
            for (int i = 0; i < 16; ++i) {
                const float dx = px[i] - lx, dy = py[i] - ly, dz = pz[i] - lz;
                const float d = (dx * dx + dy * dy) + dz * dz;
                const float m = mind[i] < d ? mind[i] : d;
                mind[i] = m;
                if (m > best) { best = m; bidx = (unsigned)(t + i * 512); }
            }
            union { float f; unsigned u; } cv; cv.f = best;   // best >= 0
            unsigned long long key = ((unsigned long long)cv.u << 32)
                                   | (0xFFFFFFFFu - bidx);    // low-idx tie-break
            DPP_RED_U64(key, >);                  // lane 63 authoritative
            if (lane == 63) wkf[(k & 1) * 8 + wid] = key;
            __syncthreads();   // compiler-blessed barrier (drain measured
                               // free: R2 == R3 at 195.5us)
            unsigned long long w = wkf[(k & 1) * 8];
#pragma unroll
            for (int i = 1; i < 8; ++i) {
                const unsigned long long o = wkf[(k & 1) * 8 + i];
                if (o > w) w = o;
            }
            const unsigned last = 0xFFFFFFFFu - (unsigned)(w & 0xFFFFFFFFu);
            lx = pts3[last * 3 + 0];              // broadcast reads
            ly = pts3[last * 3 + 1];
            lz = pts3[last * 3 + 2];
            if (t == 0) {
                cbuf[(k + 1) * 3 + 0] = lx;
                cbuf[(k + 1) * 3 + 1] = ly;
                cbuf[(k + 1) * 3 + 2] = lz;
                unsigned* dst = xchg + ((unsigned)b * KK + (unsigned)(k + 1)) * 3u;
                publish_word(dst + 0, lx);        // fire-and-forget (relaxed)
                publish_word(dst + 1, ly);
                publish_word(dst + 2, lz);
            }
        }
        __syncthreads();
        if (t < KK * 3)
            out[IDX_COUNT + b * (KK * 3) + t] = cbuf[t];

        // ------- chain done: JOIN the claim pool for this batch ----------
        // Coords from cbuf (LDS), points from pts3 (LDS) — no polling, no
        // restaging. Adds 32 CUs exactly when the tail risk peaks.
        for (;;) {
            unsigned m = 0;
            if (lane == 0) m = atomicAdd(claims + b, 1u);
            m = (unsigned)__builtin_amdgcn_readfirstlane((int)m);
            if (m >= KK) break;
            const int c = (int)m;
            const float cx = cbuf[c * 3 + 0];
            const float cy = cbuf[c * 3 + 1];
            const float cz = cbuf[c * 3 + 2];
            knn_one_center<1>(pts3, lane, cx, cy, cz,
                              out + (size_t)(b * KK + c) * PP);
        }
    } else {
        // ------------------------- KNN consumer --------------------------
        const int blk = blockIdx.x - BB;          // 0..95
        const int b = blk / KNN_PER_B;            // 3 blocks/batch
        float4* sp = (float4*)smem_raw;           // 128 KB
        const float* p = pts + (size_t)b * NN * 3;
#pragma unroll
        for (int i = 0; i < 16; ++i) {
            const int idx = t + i * 512;
            const float x = p[idx * 3 + 0], y = p[idx * 3 + 1], z = p[idx * 3 + 2];
            sp[idx] = make_float4(x, y, z, (x * x + y * y) + z * z);
        }
        __syncthreads();   // only barrier; afterwards waves run independently

        for (;;) {
            unsigned m = 0;
            if (lane == 0) m = atomicAdd(claims + b, 1u);
            m = (unsigned)__builtin_amdgcn_readfirstlane((int)m);
            if (m >= KK) break;
            const int c = (int)m;

            const unsigned* src = xchg + ((unsigned)b * KK + (unsigned)c) * 3u;
            const float cx = poll_word(src + 0);
            const float cy = poll_word(src + 1);
            const float cz = poll_word(src + 2);
            knn_one_center<0>((const float*)sp, lane, cx, cy, cz,
                              out + (size_t)(b * KK + c) * PP);
        }
    }
}

// ------------------------- fallback (ws too small) -------------------------
__global__ __launch_bounds__(512) void fps_kernel(
    const float* __restrict__ pts, float* __restrict__ out)
{
#pragma clang fp contract(off)
    const int b = blockIdx.x;
    const int t = threadIdx.x;
    const float* p = pts + (size_t)b * NN * 3;

    __shared__ float pts3[NN * 3];
    __shared__ float cbuf[KK * 3];
    __shared__ unsigned long long wk[2][8];

    float px[16], py[16], pz[16], mind[16];
#pragma unroll
    for (int i = 0; i < 16; ++i) {
        const int idx = t + i * 512;
        const float x = p[idx * 3 + 0], y = p[idx * 3 + 1], z = p[idx * 3 + 2];
        px[i] = x; py[i] = y; pz[i] = z; mind[i] = __builtin_inff();
        pts3[idx * 3 + 0] = x; pts3[idx * 3 + 1] = y; pts3[idx * 3 + 2] = z;
    }
    __syncthreads();

    float lx = pts3[0], ly = pts3[1], lz = pts3[2];
    if (t == 0) { cbuf[0] = lx; cbuf[1] = ly; cbuf[2] = lz; }
    const int lane = t & 63, wid = t >> 6;

    for (int k = 0; k < KK - 1; ++k) {
        float best = -1.0f; unsigned bidx = 0;
#pragma unroll
        for (int i = 0; i < 16; ++i) {
            const float dx = px[i] - lx, dy = py[i] - ly, dz = pz[i] - lz;
            const float d = (dx * dx + dy * dy) + dz * dz;
            const float m = mind[i] < d ? mind[i] : d;
            mind[i] = m;
            if (m > best) { best = m; bidx = (unsigned)(t + i * 512); }
        }
        union { float f; unsigned u; } cv; cv.f = best;
        unsigned long long key = ((unsigned long long)cv.u << 32)
                               | (0xFFFFFFFFu - bidx);
        DPP_RED_U64(key, >);
        if (lane == 63) wk[k & 1][wid] = key;
        __syncthreads();
        unsigned long long w = wk[k & 1][0];
#pragma unroll
        for (int i = 1; i < 8; ++i) {
            const unsigned long long o = wk[k & 1][i];
            if (o > w) w = o;
        }
        const unsigned last = 0xFFFFFFFFu - (unsigned)(w & 0xFFFFFFFFu);
        lx = pts3[last * 3 + 0];
        ly = pts3[last * 3 + 1];
        lz = pts3[last * 3 + 2];
        if (t == 0) {
            cbuf[(k + 1) * 3 + 0] = lx;
            cbuf[(k + 1) * 3 + 1] = ly;
            cbuf[(k + 1) * 3 + 2] = lz;
        }
    }
    __syncthreads();
    if (t < KK * 3)
        out[IDX_COUNT + b * (KK * 3) + t] = cbuf[t];
}

__global__ __launch_bounds__(1024) void knn_kernel(
    const float* __restrict__ pts, float* __restrict__ out)
{
#pragma clang fp contract(off)
    const int t = threadIdx.x, lane = t & 63, wid = t >> 6;
    const int blk = blockIdx.x;
    const int b = blk >> 3;
    const int bk = b * KK + (blk & 7) * 16 + wid;

    __shared__ float4 sp[NN];
    const float* p = pts + (size_t)b * NN * 3;
#pragma unroll
    for (int i = 0; i < 8; ++i) {
        const int idx = t + i * 1024;
        const float x = p[idx * 3 + 0], y = p[idx * 3 + 1], z = p[idx * 3 + 2];
        sp[idx] = make_float4(x, y, z, (x * x + y * y) + z * z);
    }

    const float cx = out[IDX_COUNT + bk * 3 + 0];
    const float cy = out[IDX_COUNT + bk * 3 + 1];
    const float cz = out[IDX_COUNT + bk * 3 + 2];
    __syncthreads();

    knn_one_center<0>((const float*)sp, lane, cx, cy, cz,
                      out + (size_t)bk * PP);
}

extern "C" void kernel_launch(void* const* d_in, const int* in_sizes, int n_in,
                              void* d_out, int out_size, void* d_ws, size_t ws_size,
                              hipStream_t stream) {
    const float* pts = (const float*)d_in[0];
    float* out = (float*)d_out;   // f32: [idx 131072 | centers 12288]

    if (ws_size >= (size_t)(CLEAR_WORDS * 4)) {
        clear_kernel<<<(CLEAR_WORDS + 1023) / 1024, 1024, 0, stream>>>(
            (unsigned*)d_ws);
        fused_kernel<<<NBLK, 512, 0, stream>>>(pts, out, (unsigned*)d_ws);
    } else {
        fps_kernel<<<BB, 512, 0, stream>>>(pts, out);
        knn_kernel<<<BB * 8, 1024, 0, stream>>>(pts, out);
    }
}